// Round 6
// baseline (427.499 us; speedup 1.0000x reference)
//
#include <hip/hip_runtime.h>
#include <hip/hip_fp16.h>
#include <math.h>

// ---------------------------------------------------------------------------
// GCN autoencoder: 4 layers (12->16->8->16->12), N=200K nodes, E=5M edges.
//
// Round 21 (= R20 retry; R20 failed to compile: __builtin_nontemporal_* does
// not accept HIP_vector_type pointers -> bit-cast through ext_vector_type).
// NON-TEMPORAL hints on every single-use stream: col/rows/mids loads in all
// gathers, partial stores + tail reads, bin/csr streams, final out store.
// Keeps each XCD's L2 reserved for the random-access gather tables (R19
// counters: 74 MB FETCH vs ~29 MB ideal = table eviction by streams).
// Structure unchanged from R19 (src-half single-visit 12-wide gathers).
// ---------------------------------------------------------------------------

#define NPB 1024               // nodes per bucket; bucket id = dst >> 10
#define MAX_NB 256             // supports N <= 262144
#define CAP 26496              // bucket region capacity (mean 25510 + ~6s)
#define BIN_CHUNK 4096         // edges per workgroup in bin_kernel
#define BIN_TH 512             // threads per workgroup in bin_kernel
#define EPT (BIN_CHUNK / BIN_TH)  // edges per thread (8)
#define MAXB CAP               // LDS col staging capacity (full bucket)

typedef int   evi4 __attribute__((ext_vector_type(4)));
typedef int   evi2 __attribute__((ext_vector_type(2)));
typedef float evf4 __attribute__((ext_vector_type(4)));
typedef float evf2 __attribute__((ext_vector_type(2)));

__device__ __forceinline__ int nt_load(const int* p) {
    return __builtin_nontemporal_load(p);
}
__device__ __forceinline__ unsigned nt_load(const unsigned* p) {
    return __builtin_nontemporal_load(p);
}
__device__ __forceinline__ float nt_load(const float* p) {
    return __builtin_nontemporal_load(p);
}
__device__ __forceinline__ int2 nt_load(const int2* p) {
    evi2 v = __builtin_nontemporal_load((const evi2*)p);
    return make_int2(v.x, v.y);
}
__device__ __forceinline__ int4 nt_load(const int4* p) {
    evi4 v = __builtin_nontemporal_load((const evi4*)p);
    return make_int4(v.x, v.y, v.z, v.w);
}
__device__ __forceinline__ float4 nt_load(const float4* p) {
    evf4 v = __builtin_nontemporal_load((const evf4*)p);
    return make_float4(v.x, v.y, v.z, v.w);
}
__device__ __forceinline__ void nt_store(int* p, int v) {
    __builtin_nontemporal_store(v, p);
}
__device__ __forceinline__ void nt_store(unsigned* p, unsigned v) {
    __builtin_nontemporal_store(v, p);
}
__device__ __forceinline__ void nt_store(float2* p, float2 v) {
    evf2 t; t.x = v.x; t.y = v.y;
    __builtin_nontemporal_store(t, (evf2*)p);
}
__device__ __forceinline__ void nt_store(float4* p, float4 v) {
    evf4 t; t.x = v.x; t.y = v.y; t.z = v.z; t.w = v.w;
    __builtin_nontemporal_store(t, (evf4*)p);
}

__global__ void init_cur_kernel(int* __restrict__ bucket_cur, int NB) {
    int t = blockIdx.x * blockDim.x + threadIdx.x;
    if (t < NB) bucket_cur[t] = t * CAP;
}

// Block-level LDS counting sort of a 4096-edge chunk (512 threads).
__global__ __launch_bounds__(BIN_TH) void bin_kernel(const int* __restrict__ src,
                                                     const int* __restrict__ dst,
                                                     int* __restrict__ bucket_cur,
                                                     unsigned int* __restrict__ binned,
                                                     int E, int NB) {
    __shared__ int h[MAX_NB];          // hist, then reused as scatter cursor
    __shared__ int scl[MAX_NB + 1];    // block-local exclusive offsets
    __shared__ int base[MAX_NB];       // global run bases
    __shared__ int sscan[256];
    __shared__ unsigned int stage[BIN_CHUNK];   // 16 KB
    __shared__ unsigned char bkt8[BIN_CHUNK];   // 4 KB bucket ids
    int cbeg = blockIdx.x * BIN_CHUNK;
    int cend = min(cbeg + BIN_CHUNK, E);
    int chunk_n = cend - cbeg;
    int tid = threadIdx.x;

    for (int t = tid; t < NB; t += BIN_TH) h[t] = 0;
    __syncthreads();
    int myd[EPT];
#pragma unroll
    for (int j = 0; j < EPT; j++) {
        int e = cbeg + tid + j * BIN_TH;
        if (e < cend) {
            myd[j] = nt_load(dst + e);
            atomicAdd(&h[myd[j] >> 10], 1);
        }
    }
    __syncthreads();
    int v = (tid < NB) ? h[tid] : 0;
    if (tid < 256) sscan[tid] = v;
    __syncthreads();
    for (int off = 1; off < 256; off <<= 1) {
        int t = (tid >= off && tid < 256) ? sscan[tid - off] : 0;
        __syncthreads();
        if (tid < 256) sscan[tid] += t;
        __syncthreads();
    }
    if (tid < NB) {
        scl[tid] = sscan[tid] - v;
        base[tid] = v ? atomicAdd(&bucket_cur[tid], v) : 0;
    }
    if (tid == 0) scl[NB] = chunk_n;
    __syncthreads();
    for (int t = tid; t < NB; t += BIN_TH) h[t] = 0;  // reuse as cursor
    __syncthreads();
#pragma unroll
    for (int j = 0; j < EPT; j++) {
        int e = cbeg + tid + j * BIN_TH;
        if (e < cend) {
            int d = myd[j];
            int bkt = d >> 10;
            int pos = scl[bkt] + atomicAdd(&h[bkt], 1);
            stage[pos] = ((unsigned)nt_load(src + e) << 10) | (unsigned)(d & 1023);
            bkt8[pos] = (unsigned char)bkt;
        }
    }
    __syncthreads();
    for (int k = tid; k < chunk_n; k += BIN_TH) {
        int bkt = bkt8[k];
        nt_store(binned + base[bkt] + (k - scl[bkt]), stage[k]);
    }
}

// One WG per FULL bucket (1024 nodes, 1024 threads): per-node count + scan,
// rows/mids/dis emit, 2-way src-half partitioned scatter into LDS colbuf,
// coalesced flush. FUSED T1 tail: T1 = x*dis, 12 feats in 32B-padded rows.
__global__ __launch_bounds__(1024) void csr_bucket_t1_kernel(
    const unsigned int* __restrict__ binned,
    const int* __restrict__ bucket_cur,
    int2* __restrict__ rows, int* __restrict__ mids, float* __restrict__ dis,
    int* __restrict__ col,
    const float* __restrict__ x,
    __half* __restrict__ xls, int N, int halfN) {
    __shared__ int cnt[NPB];
    __shared__ int cnt0[NPB];
    __shared__ int curA[NPB];
    __shared__ int curB[NPB];
    __shared__ int colbuf[MAXB];   // 104 KB (total ~119.5 KB LDS)
    int b = blockIdx.x;
    int nbase = b << 10;
    int nlocal = min(NPB, N - nbase);
    int beg = b * CAP;
    int bsize = bucket_cur[b] - beg;
    int tid = threadIdx.x;

    cnt[tid] = 0;
    cnt0[tid] = 0;
    __syncthreads();
    for (int k = tid; k < bsize; k += 1024) {
        unsigned rec = nt_load(binned + beg + k);
        int l = rec & 1023u;
        int s = (int)(rec >> 10);
        atomicAdd(&cnt[l], 1);
        if (s < halfN) atomicAdd(&cnt0[l], 1);
    }
    __syncthreads();
    int v = cnt[tid];
    int v0 = cnt0[tid];
    curA[tid] = v;
    __syncthreads();
    for (int off = 1; off < 1024; off <<= 1) {
        int t = (tid >= off) ? curA[tid - off] : 0;
        __syncthreads();
        curA[tid] += t;
        __syncthreads();
    }
    int excl = curA[tid] - v;
    float d = 1.0f / sqrtf((float)(v + 1));  // +1 self-loop
    if (tid < nlocal) {
        rows[nbase + tid] = make_int2(beg + excl, beg + excl + v);
        mids[nbase + tid] = beg + excl + v0;
        dis[nbase + tid] = d;
    }
    __syncthreads();
    curA[tid] = excl;          // cursor for src < halfN
    curB[tid] = excl + v0;     // cursor for src >= halfN
    __syncthreads();
    if (bsize <= MAXB) {
        for (int k = tid; k < bsize; k += 1024) {
            unsigned rec = nt_load(binned + beg + k);
            int l = rec & 1023u;
            int s = (int)(rec >> 10);
            int pos = (s < halfN) ? atomicAdd(&curA[l], 1)
                                  : atomicAdd(&curB[l], 1);
            colbuf[pos] = s;
        }
        __syncthreads();
        for (int k = tid; k < bsize; k += 1024) nt_store(col + beg + k, colbuf[k]);
    } else {  // cannot trigger with CAP sizing; correctness fallback
        for (int k = tid; k < bsize; k += 1024) {
            unsigned rec = binned[beg + k];
            int l = rec & 1023u;
            int s = (int)(rec >> 10);
            int pos = (s < halfN) ? atomicAdd(&curA[l], 1)
                                  : atomicAdd(&curB[l], 1);
            col[beg + pos] = s;
        }
    }
    // ---- fused T1 = x * dis, 12 feats in 32B-padded rows (stride 16) ----
    if (tid < nlocal) {
        int i = nbase + tid;
        float h[12];
#pragma unroll
        for (int k = 0; k < 12; k++) h[k] = nt_load(x + (size_t)i * 12 + k);
        __half2* x2 = (__half2*)xls;
#pragma unroll
        for (int k = 0; k < 6; k++) {
            x2[(size_t)i * 8 + k] =
                __floats2half2_rn(h[2 * k] * d, h[2 * k + 1] * d);
        }
    }
}

// Accumulate one source node's P half2-features (row stride S half2s).
template <int P, int S>
__device__ __forceinline__ void acc_node(const __half2* __restrict__ x2, int c,
                                         float2 (&acc)[P]) {
    __half2 t[P];
#pragma unroll
    for (int k = 0; k < P; k++) t[k] = x2[(size_t)c * S + k];
#pragma unroll
    for (int k = 0; k < P; k++) {
        float2 v = __half22float2(t[k]);
        acc[k].x += v.x;
        acc[k].y += v.y;
    }
}

template <int P, int S>
__device__ __forceinline__ void acc_quad(const __half2* __restrict__ x2, int4 c,
                                         float2 (&acc)[P]) {
    __half2 t[4][P];
#pragma unroll
    for (int k = 0; k < P; k++) t[0][k] = x2[(size_t)c.x * S + k];
#pragma unroll
    for (int k = 0; k < P; k++) t[1][k] = x2[(size_t)c.y * S + k];
#pragma unroll
    for (int k = 0; k < P; k++) t[2][k] = x2[(size_t)c.z * S + k];
#pragma unroll
    for (int k = 0; k < P; k++) t[3][k] = x2[(size_t)c.w * S + k];
#pragma unroll
    for (int k = 0; k < P; k++) {
        float2 a0 = __half22float2(t[0][k]), a1 = __half22float2(t[1][k]);
        float2 a2 = __half22float2(t[2][k]), a3 = __half22float2(t[3][k]);
        acc[k].x += (a0.x + a1.x) + (a2.x + a3.x);
        acc[k].y += (a0.y + a1.y) + (a2.y + a3.y);
    }
}

// Core gather over an explicit [beg,end) col sub-range: lane-pair per node,
// 16B-aligned int4 col quads (NT loads), UN quads in flight per lane,
// shfl-combined. UN=3 for P<=4, UN=2 for P=6 (bound VGPRs).
// Self-loop contribution added iff `self` (by lane 0 only).
template <int C, int S>
__device__ __forceinline__ void gather_acc_rng(
    int i, int p, int beg, int end, bool self,
    const int* __restrict__ col, const __half2* __restrict__ x2,
    float2 (&acc)[C / 2]) {
    constexpr int P = C / 2;
    constexpr int UN = (P >= 6) ? 2 : 3;
#pragma unroll
    for (int k = 0; k < P; k++) {
        if (self && p == 0) acc[k] = __half22float2(x2[(size_t)i * S + k]);
        else acc[k] = make_float2(0.0f, 0.0f);
    }
    int nedge = end - beg;
    int pre = (4 - (beg & 3)) & 3;
    if (pre > nedge) pre = nedge;
    for (int j = p; j < pre; j += 2) acc_node<P, S>(x2, nt_load(col + beg + j), acc);
    int abeg = beg + pre;
    int nq = (end - abeg) >> 2;  // full aligned quads
    int q = p;
    for (; q + 2 * (UN - 1) < nq; q += 2 * UN) {
        int4 cs[UN];
#pragma unroll
        for (int u = 0; u < UN; u++)
            cs[u] = nt_load(reinterpret_cast<const int4*>(col + abeg + 4 * (q + 2 * u)));
#pragma unroll
        for (int u = 0; u < UN; u++) acc_quad<P, S>(x2, cs[u], acc);
    }
    for (; q < nq; q += 2) {
        int4 ca = nt_load(reinterpret_cast<const int4*>(col + abeg + 4 * q));
        acc_quad<P, S>(x2, ca, acc);
    }
    int tbeg = abeg + 4 * nq;
    for (int j = tbeg + p; j < end; j += 2) acc_node<P, S>(x2, nt_load(col + j), acc);
#pragma unroll
    for (int k = 0; k < P; k++) {
        acc[k].x += __shfl_xor(acc[k].x, 1);
        acc[k].y += __shfl_xor(acc[k].y, 1);
    }
}

// 12-wide single-visit gather, src-half partitioned. chunk = (blockIdx&7)>=4
// (XCD-affine): chunk c walks sublist c of each row against table half c
// (3.2 MB slice, L2-resident). Writes raw partial sums (no dis scale).
__global__ __launch_bounds__(256) void gather12h_kernel(
    const int2* __restrict__ rows, const int* __restrict__ mids,
    const int* __restrict__ col, const __half* __restrict__ xin,
    float* __restrict__ part0, float* __restrict__ part1, int N, int halfN) {
    int grp = blockIdx.x >> 3;
    int sub = blockIdx.x & 7;
    int chunk = sub >> 2;
    int range = (grp << 2) + (sub & 3);
    int t2 = range * 256 + (int)threadIdx.x;
    int i = t2 >> 1;
    int p = t2 & 1;
    if (i >= N) return;
    int2 r = nt_load(rows + i);
    int m = nt_load(mids + i);
    int beg = chunk ? m : r.x;
    int end = chunk ? r.y : m;
    bool self = chunk ? (i >= halfN) : (i < halfN);
    float2 acc[6];
    gather_acc_rng<12, 8>(i, p, beg, end, self, col, (const __half2*)xin, acc);
    float* part = chunk ? part1 : part0;
    float2* ap = (float2*)(part + (size_t)i * 12);
#pragma unroll
    for (int k = 0; k < 6; k++) {
        if ((k & 1) == p) nt_store(ap + k, acc[k]);
    }
}

// Layer-1 tail: A1 = (part0+part1)*d -> relu(A1@W1+b1) -> @W2 -> *dis
// -> T2 table (8-wide fp16, 16B rows).
__global__ __launch_bounds__(256) void transform12_kernel(
    const float* __restrict__ p0, const float* __restrict__ p1,
    const float* __restrict__ b1, const float* __restrict__ W1,
    const float* __restrict__ W2, const float* __restrict__ dis,
    __half* __restrict__ xout, int N) {
    __shared__ float sW1[12 * 16];
    __shared__ float sW2[16 * 8];
    __shared__ float sB[16];
    if (threadIdx.x < 192) sW1[threadIdx.x] = W1[threadIdx.x];
    if (threadIdx.x < 128) sW2[threadIdx.x] = W2[threadIdx.x];
    if (threadIdx.x < 16) sB[threadIdx.x] = b1[threadIdx.x];
    __syncthreads();
    int i = blockIdx.x * blockDim.x + threadIdx.x;
    if (i >= N) return;
    float d = dis[i];
    float A[12];
    const float4* a4 = (const float4*)(p0 + (size_t)i * 12);
    const float4* b4 = (const float4*)(p1 + (size_t)i * 12);
#pragma unroll
    for (int q = 0; q < 3; q++) {
        float4 va = nt_load(a4 + q), vb = nt_load(b4 + q);
        A[4 * q + 0] = (va.x + vb.x) * d;
        A[4 * q + 1] = (va.y + vb.y) * d;
        A[4 * q + 2] = (va.z + vb.z) * d;
        A[4 * q + 3] = (va.w + vb.w) * d;
    }
    float h[16];
#pragma unroll
    for (int f = 0; f < 16; f++) {
        float acc = sB[f];
#pragma unroll
        for (int k = 0; k < 12; k++) acc = fmaf(A[k], sW1[k * 16 + f], acc);
        h[f] = fmaxf(acc, 0.0f);
    }
    __half2* x2 = (__half2*)xout;
#pragma unroll
    for (int k2 = 0; k2 < 4; k2++) {
        float o0 = 0.0f, o1 = 0.0f;
#pragma unroll
        for (int k = 0; k < 16; k++) {
            o0 = fmaf(h[k], sW2[k * 8 + 2 * k2], o0);
            o1 = fmaf(h[k], sW2[k * 8 + 2 * k2 + 1], o1);
        }
        x2[(size_t)i * 4 + k2] = __floats2half2_rn(o0 * d, o1 * d);
    }
}

// Layer-2 gather (8-wide, single pass): T3 = (acc*d + b2) * d -> fp16 table.
__global__ __launch_bounds__(256) void gather8_t3_kernel(
    const int2* __restrict__ rows, const int* __restrict__ col,
    const float* __restrict__ dis, const __half* __restrict__ xin,
    const float* __restrict__ b2, __half* __restrict__ xout, int N) {
    int tid = blockIdx.x * blockDim.x + threadIdx.x;
    int i = tid >> 1;
    int p = tid & 1;
    if (i >= N) return;
    int2 r = nt_load(rows + i);
    float2 acc[4];
    gather_acc_rng<8, 4>(i, p, r.x, r.y, true, col, (const __half2*)xin, acc);
    float d = dis[i];
    __half2* x2o = (__half2*)xout;
#pragma unroll
    for (int k = 0; k < 4; k++) {
        if ((k >> 1) == p) {
            x2o[(size_t)i * 4 + k] =
                __floats2half2_rn((acc[k].x * d + b2[2 * k]) * d,
                                  (acc[k].y * d + b2[2 * k + 1]) * d);
        }
    }
}

// Layer-3 gather (8-wide, single pass) with fused epilogue:
//   A3 = acc*d; h = relu(A3@W3 + b3) (16); T4 = (h@W4)*d, 12 feats in
//   32B-padded rows. Lane p computes hidden slice [8p,8p+8), partial
//   12-outputs, shfl-combine; lane 0 writes feats 0..7, lane 1 feats 8..11.
__global__ __launch_bounds__(256) void gather8_t4_kernel(
    const int2* __restrict__ rows, const int* __restrict__ col,
    const float* __restrict__ dis, const __half* __restrict__ xin,
    const float* __restrict__ b3, const float* __restrict__ W3,
    const float* __restrict__ W4, __half* __restrict__ xout, int N) {
    __shared__ float sW3[8 * 16];
    __shared__ float sW4[16 * 12];
    __shared__ float sB[16];
    if (threadIdx.x < 128) sW3[threadIdx.x] = W3[threadIdx.x];
    if (threadIdx.x < 192) sW4[threadIdx.x] = W4[threadIdx.x];
    if (threadIdx.x < 16) sB[threadIdx.x] = b3[threadIdx.x];
    __syncthreads();
    int tid = blockIdx.x * blockDim.x + threadIdx.x;
    int i = tid >> 1;
    int p = tid & 1;
    if (i >= N) return;
    int2 r = nt_load(rows + i);
    float2 acc[4];
    gather_acc_rng<8, 4>(i, p, r.x, r.y, true, col, (const __half2*)xin, acc);
    float d = dis[i];
    float A[8];
#pragma unroll
    for (int k = 0; k < 4; k++) {
        A[2 * k] = acc[k].x * d;
        A[2 * k + 1] = acc[k].y * d;
    }
    float h[8];
#pragma unroll
    for (int f = 0; f < 8; f++) {
        float a = sB[p * 8 + f];
#pragma unroll
        for (int k = 0; k < 8; k++) a = fmaf(A[k], sW3[k * 16 + p * 8 + f], a);
        h[f] = fmaxf(a, 0.0f);
    }
    float o[12];
#pragma unroll
    for (int j = 0; j < 12; j++) {
        float a = 0.0f;
#pragma unroll
        for (int f = 0; f < 8; f++) a = fmaf(h[f], sW4[(p * 8 + f) * 12 + j], a);
        o[j] = a;
    }
#pragma unroll
    for (int j = 0; j < 12; j++) o[j] += __shfl_xor(o[j], 1);
    __half2* x2o = (__half2*)xout;
    if (p == 0) {
#pragma unroll
        for (int k = 0; k < 4; k++) {
            x2o[(size_t)i * 8 + k] =
                __floats2half2_rn(o[2 * k] * d, o[2 * k + 1] * d);
        }
    } else {
#pragma unroll
        for (int k = 0; k < 2; k++) {
            x2o[(size_t)i * 8 + 4 + k] =
                __floats2half2_rn(o[8 + 2 * k] * d, o[9 + 2 * k] * d);
        }
    }
}

// Layer-4 tail: out = sigmoid((part0+part1)*d + b4), 12-wide.
__global__ __launch_bounds__(256) void combine_sig_kernel(
    const float* __restrict__ p0, const float* __restrict__ p1,
    const float* __restrict__ dis, const float* __restrict__ bias,
    float* __restrict__ out, int N) {
    __shared__ float sB[12];
    if (threadIdx.x < 12) sB[threadIdx.x] = bias[threadIdx.x];
    __syncthreads();
    int i = blockIdx.x * blockDim.x + threadIdx.x;
    if (i >= N) return;
    float d = dis[i];
    const float4* a4 = (const float4*)(p0 + (size_t)i * 12);
    const float4* b4 = (const float4*)(p1 + (size_t)i * 12);
    float4* o4 = (float4*)(out + (size_t)i * 12);
#pragma unroll
    for (int q = 0; q < 3; q++) {
        float4 va = nt_load(a4 + q), vb = nt_load(b4 + q);
        float4 r;
        r.x = 1.0f / (1.0f + expf(-((va.x + vb.x) * d + sB[4 * q + 0])));
        r.y = 1.0f / (1.0f + expf(-((va.y + vb.y) * d + sB[4 * q + 1])));
        r.z = 1.0f / (1.0f + expf(-((va.z + vb.z) * d + sB[4 * q + 2])));
        r.w = 1.0f / (1.0f + expf(-((va.w + vb.w) * d + sB[4 * q + 3])));
        nt_store(o4 + q, r);
    }
}

static inline size_t align_up(size_t v, size_t a) { return (v + a - 1) & ~(a - 1); }

extern "C" void kernel_launch(void* const* d_in, const int* in_sizes, int n_in,
                              void* d_out, int out_size, void* d_ws, size_t ws_size,
                              hipStream_t stream) {
    const float* x  = (const float*)d_in[0];
    const int*   ei = (const int*)d_in[1];
    const float* W1 = (const float*)d_in[2];
    const float* b1 = (const float*)d_in[3];
    const float* W2 = (const float*)d_in[4];
    const float* b2 = (const float*)d_in[5];
    const float* W3 = (const float*)d_in[6];
    const float* b3 = (const float*)d_in[7];
    const float* W4 = (const float*)d_in[8];
    const float* b4 = (const float*)d_in[9];
    float* out = (float*)d_out;

    const int N = in_sizes[0] / 12;
    const int E = in_sizes[1] / 2;
    const int halfN = N >> 1;
    const int* src = ei;       // edge_index[0]
    const int* dst = ei + E;   // edge_index[1]
    const int NB = (N + NPB - 1) / NPB;  // 196

    // Workspace carve-up (~58 MB); partials alias the dead binned[] region.
    char* ws = (char*)d_ws;
    size_t off = 0;
    int* bucket_cur = (int*)(ws + off);   off = align_up(off + (size_t)NB * 4, 256);
    int2* rows = (int2*)(ws + off);       off = align_up(off + (size_t)N * 8, 256);
    int* mids = (int*)(ws + off);         off = align_up(off + (size_t)N * 4, 256);
    float* dis = (float*)(ws + off);      off = align_up(off + (size_t)N * 4, 256);
    unsigned int* binned = (unsigned int*)(ws + off);
    off = align_up(off + ((size_t)NB * CAP + 4096) * 4, 256);
    int* col = (int*)(ws + off);          off = align_up(off + ((size_t)NB * CAP + 4096) * 4, 256);
    __half* xls = (__half*)(ws + off);    off = align_up(off + (size_t)N * 16 * 2, 256);
    __half* xls2 = (__half*)(ws + off);   off = align_up(off + (size_t)N * 16 * 2, 256);
    (void)ws_size; (void)n_in; (void)out_size;

    // Partials (2 x N x 12 fp32 = 19.2 MB) alias binned (20.7 MB): binned is
    // dead after csr_bucket_t1_kernel completes (stream-ordered).
    float* part0 = (float*)binned;
    float* part1 = part0 + (size_t)N * 12;

    const int B = 256;
    auto blocks = [&](long long n) { return (int)((n + B - 1) / B); };
    int nb2 = blocks(2LL * N);          // ranges for merged gather
    nb2 = (nb2 + 3) & ~3;               // multiple of 4
    const int G2 = nb2 * 2;             // merged-gather grid (mult of 8)

    // --- CSR build (src-half partitioned rows) + fused T1 = x*dis --------
    init_cur_kernel<<<1, 256, 0, stream>>>(bucket_cur, NB);
    bin_kernel<<<(E + BIN_CHUNK - 1) / BIN_CHUNK, BIN_TH, 0, stream>>>(src, dst, bucket_cur, binned, E, NB);
    csr_bucket_t1_kernel<<<NB, 1024, 0, stream>>>(binned, bucket_cur, rows, mids, dis,
                                                  col, x, xls, N, halfN);

    // --- Layer 1: single-visit src-half gather (12-wide) -> partials -----
    gather12h_kernel<<<G2, B, 0, stream>>>(rows, mids, col, xls, part0, part1, N, halfN);

    // --- Layer-1 tail: relu(((p0+p1)*d)@W1+b1)@W2*dis -> T2 (xls2) -------
    transform12_kernel<<<blocks(N), B, 0, stream>>>(part0, part1, b1, W1, W2, dis, xls2, N);

    // --- Layer 2: single-pass 8-wide gather -> T3 (xls) ------------------
    gather8_t3_kernel<<<blocks(2LL * N), B, 0, stream>>>(rows, col, dis, xls2, b2, xls, N);

    // --- Layer 3: single-pass 8-wide gather + fused W3/relu/W4 -> T4 (xls2)
    gather8_t4_kernel<<<blocks(2LL * N), B, 0, stream>>>(rows, col, dis, xls, b3, W3, W4,
                                                         xls2, N);

    // --- Layer 4: single-visit src-half gather (12-wide) -> partials -----
    gather12h_kernel<<<G2, B, 0, stream>>>(rows, mids, col, xls2, part0, part1, N, halfN);

    // --- Layer-4 tail: sigmoid((p0+p1)*d + b4) -> out --------------------
    combine_sig_kernel<<<blocks(N), B, 0, stream>>>(part0, part1, dis, b4, out, N);
}

// Round 7
// 365.601 us; speedup vs baseline: 1.1693x; 1.1693x over previous
//
#include <hip/hip_runtime.h>
#include <hip/hip_fp16.h>
#include <math.h>

// ---------------------------------------------------------------------------
// GCN autoencoder: 4 layers (12->16->8->16->12), N=200K nodes, E=5M edges.
//
// Round 22 (on R19's 360 us; R21 NT hints regressed to 427 -> fully
// reverted): 4-way SRC-QUARTER partitioned single-visit gathers for the
// 12-wide layers (L1, L4). R19 counters showed 26 MB of table re-fetch per
// gather (3.2 MB slice does not stay resident in 4 MB L2 next to ~5 MB of
// streaming col/partials). Quarter slices = 1.6 MB -> resident; cold fetch
// halves (2 XCDs per chunk). Still exactly 1 visit/edge. CSR build emits
// int4 quarter boundaries (1 LDS atomic/edge counting). Partials 4x (WRITE
// ~38 MB, +6 us streaming) -- net win if re-fetch dies. Runtime ws_size
// check falls back to 2-way partials-in-binned if workspace is tight.
// ---------------------------------------------------------------------------

#define NPB 1024               // nodes per bucket; bucket id = dst >> 10
#define MAX_NB 256             // supports N <= 262144
#define CAP 26496              // bucket region capacity (mean 25510 + ~6s)
#define BIN_CHUNK 4096         // edges per workgroup in bin_kernel
#define BIN_TH 512             // threads per workgroup in bin_kernel
#define EPT (BIN_CHUNK / BIN_TH)  // edges per thread (8)
#define MAXB CAP               // LDS col staging capacity (full bucket)

__global__ void init_cur_kernel(int* __restrict__ bucket_cur, int NB) {
    int t = blockIdx.x * blockDim.x + threadIdx.x;
    if (t < NB) bucket_cur[t] = t * CAP;
}

// Block-level LDS counting sort of a 4096-edge chunk (512 threads).
__global__ __launch_bounds__(BIN_TH) void bin_kernel(const int* __restrict__ src,
                                                     const int* __restrict__ dst,
                                                     int* __restrict__ bucket_cur,
                                                     unsigned int* __restrict__ binned,
                                                     int E, int NB) {
    __shared__ int h[MAX_NB];          // hist, then reused as scatter cursor
    __shared__ int scl[MAX_NB + 1];    // block-local exclusive offsets
    __shared__ int base[MAX_NB];       // global run bases
    __shared__ int sscan[256];
    __shared__ unsigned int stage[BIN_CHUNK];   // 16 KB
    __shared__ unsigned char bkt8[BIN_CHUNK];   // 4 KB bucket ids
    int cbeg = blockIdx.x * BIN_CHUNK;
    int cend = min(cbeg + BIN_CHUNK, E);
    int chunk_n = cend - cbeg;
    int tid = threadIdx.x;

    for (int t = tid; t < NB; t += BIN_TH) h[t] = 0;
    __syncthreads();
    int myd[EPT];
#pragma unroll
    for (int j = 0; j < EPT; j++) {
        int e = cbeg + tid + j * BIN_TH;
        if (e < cend) {
            myd[j] = dst[e];
            atomicAdd(&h[myd[j] >> 10], 1);
        }
    }
    __syncthreads();
    int v = (tid < NB) ? h[tid] : 0;
    if (tid < 256) sscan[tid] = v;
    __syncthreads();
    for (int off = 1; off < 256; off <<= 1) {
        int t = (tid >= off && tid < 256) ? sscan[tid - off] : 0;
        __syncthreads();
        if (tid < 256) sscan[tid] += t;
        __syncthreads();
    }
    if (tid < NB) {
        scl[tid] = sscan[tid] - v;
        base[tid] = v ? atomicAdd(&bucket_cur[tid], v) : 0;
    }
    if (tid == 0) scl[NB] = chunk_n;
    __syncthreads();
    for (int t = tid; t < NB; t += BIN_TH) h[t] = 0;  // reuse as cursor
    __syncthreads();
#pragma unroll
    for (int j = 0; j < EPT; j++) {
        int e = cbeg + tid + j * BIN_TH;
        if (e < cend) {
            int d = myd[j];
            int bkt = d >> 10;
            int pos = scl[bkt] + atomicAdd(&h[bkt], 1);
            stage[pos] = ((unsigned)src[e] << 10) | (unsigned)(d & 1023);
            bkt8[pos] = (unsigned char)bkt;
        }
    }
    __syncthreads();
    for (int k = tid; k < chunk_n; k += BIN_TH) {
        int bkt = bkt8[k];
        binned[base[bkt] + (k - scl[bkt])] = stage[k];
    }
}

// One WG per FULL bucket (1024 nodes, 1024 threads): per-(node,quarter)
// count (ONE LDS atomic/edge), scan, rows/qmids/dis emit, 4-way src-quarter
// partitioned scatter into LDS colbuf, coalesced flush.
// FUSED T1 tail: T1 = x*dis, 12 feats in 32B-padded rows.
__global__ __launch_bounds__(1024) void csr_bucket_t1_kernel(
    const unsigned int* __restrict__ binned,
    const int* __restrict__ bucket_cur,
    int2* __restrict__ rows, int4* __restrict__ qmids, float* __restrict__ dis,
    int* __restrict__ col,
    const float* __restrict__ x,
    __half* __restrict__ xls, int N, int qN) {
    __shared__ int cnt4[4 * NPB];  // counts -> cursors (16 KB)
    __shared__ int sc[NPB];        // scan workspace (4 KB)
    __shared__ int colbuf[MAXB];   // 104 KB  (total ~124 KB LDS)
    int b = blockIdx.x;
    int nbase = b << 10;
    int nlocal = min(NPB, N - nbase);
    int beg = b * CAP;
    int bsize = bucket_cur[b] - beg;
    int tid = threadIdx.x;

    for (int t = tid; t < 4 * NPB; t += 1024) cnt4[t] = 0;
    __syncthreads();
    for (int k = tid; k < bsize; k += 1024) {
        unsigned rec = binned[beg + k];
        int l = rec & 1023u;
        int s = (int)(rec >> 10);
        int q = s / qN;  // 0..3
        atomicAdd(&cnt4[q * NPB + l], 1);
    }
    __syncthreads();
    int c0 = cnt4[tid];
    int c1 = cnt4[NPB + tid];
    int c2 = cnt4[2 * NPB + tid];
    int c3 = cnt4[3 * NPB + tid];
    int v = c0 + c1 + c2 + c3;
    sc[tid] = v;
    __syncthreads();
    for (int off = 1; off < 1024; off <<= 1) {
        int t = (tid >= off) ? sc[tid - off] : 0;
        __syncthreads();
        sc[tid] += t;
        __syncthreads();
    }
    int excl = sc[tid] - v;
    float d = 1.0f / sqrtf((float)(v + 1));  // +1 self-loop
    if (tid < nlocal) {
        rows[nbase + tid] = make_int2(beg + excl, beg + excl + v);
        qmids[nbase + tid] = make_int4(beg + excl + c0,
                                       beg + excl + c0 + c1,
                                       beg + excl + c0 + c1 + c2, 0);
        dis[nbase + tid] = d;
    }
    __syncthreads();
    cnt4[tid] = excl;                           // cursor q0
    cnt4[NPB + tid] = excl + c0;                // cursor q1
    cnt4[2 * NPB + tid] = excl + c0 + c1;       // cursor q2
    cnt4[3 * NPB + tid] = excl + c0 + c1 + c2;  // cursor q3
    __syncthreads();
    if (bsize <= MAXB) {
        for (int k = tid; k < bsize; k += 1024) {
            unsigned rec = binned[beg + k];
            int l = rec & 1023u;
            int s = (int)(rec >> 10);
            int q = s / qN;
            int pos = atomicAdd(&cnt4[q * NPB + l], 1);
            colbuf[pos] = s;
        }
        __syncthreads();
        for (int k = tid; k < bsize; k += 1024) col[beg + k] = colbuf[k];
    } else {  // cannot trigger with CAP sizing; correctness fallback
        for (int k = tid; k < bsize; k += 1024) {
            unsigned rec = binned[beg + k];
            int l = rec & 1023u;
            int s = (int)(rec >> 10);
            int q = s / qN;
            int pos = atomicAdd(&cnt4[q * NPB + l], 1);
            col[beg + pos] = s;
        }
    }
    // ---- fused T1 = x * dis, 12 feats in 32B-padded rows (stride 16) ----
    if (tid < nlocal) {
        int i = nbase + tid;
        float h[12];
#pragma unroll
        for (int k = 0; k < 12; k++) h[k] = x[(size_t)i * 12 + k];
        __half2* x2 = (__half2*)xls;
#pragma unroll
        for (int k = 0; k < 6; k++) {
            x2[(size_t)i * 8 + k] =
                __floats2half2_rn(h[2 * k] * d, h[2 * k + 1] * d);
        }
    }
}

// Accumulate one source node's P half2-features (row stride S half2s).
template <int P, int S>
__device__ __forceinline__ void acc_node(const __half2* __restrict__ x2, int c,
                                         float2 (&acc)[P]) {
    __half2 t[P];
#pragma unroll
    for (int k = 0; k < P; k++) t[k] = x2[(size_t)c * S + k];
#pragma unroll
    for (int k = 0; k < P; k++) {
        float2 v = __half22float2(t[k]);
        acc[k].x += v.x;
        acc[k].y += v.y;
    }
}

template <int P, int S>
__device__ __forceinline__ void acc_quad(const __half2* __restrict__ x2, int4 c,
                                         float2 (&acc)[P]) {
    __half2 t[4][P];
#pragma unroll
    for (int k = 0; k < P; k++) t[0][k] = x2[(size_t)c.x * S + k];
#pragma unroll
    for (int k = 0; k < P; k++) t[1][k] = x2[(size_t)c.y * S + k];
#pragma unroll
    for (int k = 0; k < P; k++) t[2][k] = x2[(size_t)c.z * S + k];
#pragma unroll
    for (int k = 0; k < P; k++) t[3][k] = x2[(size_t)c.w * S + k];
#pragma unroll
    for (int k = 0; k < P; k++) {
        float2 a0 = __half22float2(t[0][k]), a1 = __half22float2(t[1][k]);
        float2 a2 = __half22float2(t[2][k]), a3 = __half22float2(t[3][k]);
        acc[k].x += (a0.x + a1.x) + (a2.x + a3.x);
        acc[k].y += (a0.y + a1.y) + (a2.y + a3.y);
    }
}

// Core gather over an explicit [beg,end) col sub-range: lane-pair per node,
// 16B-aligned int4 col quads, UN quads in flight per lane, shfl-combined.
// UN=3 for P<=4, UN=2 for P=6 (bound VGPRs).
// Self-loop contribution added iff `self` (by lane 0 only).
template <int C, int S>
__device__ __forceinline__ void gather_acc_rng(
    int i, int p, int beg, int end, bool self,
    const int* __restrict__ col, const __half2* __restrict__ x2,
    float2 (&acc)[C / 2]) {
    constexpr int P = C / 2;
    constexpr int UN = (P >= 6) ? 2 : 3;
#pragma unroll
    for (int k = 0; k < P; k++) {
        if (self && p == 0) acc[k] = __half22float2(x2[(size_t)i * S + k]);
        else acc[k] = make_float2(0.0f, 0.0f);
    }
    int nedge = end - beg;
    int pre = (4 - (beg & 3)) & 3;
    if (pre > nedge) pre = nedge;
    for (int j = p; j < pre; j += 2) acc_node<P, S>(x2, col[beg + j], acc);
    int abeg = beg + pre;
    int nq = (end - abeg) >> 2;  // full aligned quads
    int q = p;
    for (; q + 2 * (UN - 1) < nq; q += 2 * UN) {
        int4 cs[UN];
#pragma unroll
        for (int u = 0; u < UN; u++)
            cs[u] = *reinterpret_cast<const int4*>(col + abeg + 4 * (q + 2 * u));
#pragma unroll
        for (int u = 0; u < UN; u++) acc_quad<P, S>(x2, cs[u], acc);
    }
    for (; q < nq; q += 2) {
        int4 ca = *reinterpret_cast<const int4*>(col + abeg + 4 * q);
        acc_quad<P, S>(x2, ca, acc);
    }
    int tbeg = abeg + 4 * nq;
    for (int j = tbeg + p; j < end; j += 2) acc_node<P, S>(x2, col[j], acc);
#pragma unroll
    for (int k = 0; k < P; k++) {
        acc[k].x += __shfl_xor(acc[k].x, 1);
        acc[k].y += __shfl_xor(acc[k].y, 1);
    }
}

// 12-wide single-visit gather, src-partitioned into NC chunks (NC = 4 or 2).
// XCD-affine: chunk = (blockIdx&7)>>1 for NC=4 (2 XCDs/chunk, 1.6 MB slice)
// or >>2 for NC=2 (4 XCDs/chunk, 3.2 MB slice). Writes raw partial sums.
template <int NC>
__global__ __launch_bounds__(256) void gather12p_kernel(
    const int2* __restrict__ rows, const int4* __restrict__ qmids,
    const int* __restrict__ col, const __half* __restrict__ xin,
    float* __restrict__ part0, float* __restrict__ part1,
    float* __restrict__ part2, float* __restrict__ part3, int N, int qN) {
    int grp = blockIdx.x >> 3;
    int sub = blockIdx.x & 7;
    int chunk, range;
    if (NC == 4) {
        chunk = sub >> 1;
        range = (grp << 1) + (sub & 1);
    } else {
        chunk = sub >> 2;
        range = (grp << 2) + (sub & 3);
    }
    int t2 = range * 256 + (int)threadIdx.x;
    int i = t2 >> 1;
    int p = t2 & 1;
    if (i >= N) return;
    int2 r = rows[i];
    int4 qm = qmids[i];
    int beg, end;
    if (NC == 4) {
        beg = (chunk == 0) ? r.x : (chunk == 1) ? qm.x : (chunk == 2) ? qm.y : qm.z;
        end = (chunk == 0) ? qm.x : (chunk == 1) ? qm.y : (chunk == 2) ? qm.z : r.y;
    } else {
        beg = chunk ? qm.y : r.x;
        end = chunk ? r.y : qm.y;
    }
    int qi = i / qN;
    bool self = (NC == 4) ? (qi == chunk) : ((qi >> 1) == chunk);
    float2 acc[6];
    gather_acc_rng<12, 8>(i, p, beg, end, self, col, (const __half2*)xin, acc);
    float* part = (chunk == 0) ? part0 : (chunk == 1) ? part1
                 : (chunk == 2) ? part2 : part3;
    float2* ap = (float2*)(part + (size_t)i * 12);
#pragma unroll
    for (int k = 0; k < 6; k++) {
        if ((k & 1) == p) ap[k] = acc[k];
    }
}

// Layer-1 tail: A1 = (sum of NP partials)*d -> relu(A1@W1+b1) -> @W2 -> *dis
// -> T2 table (8-wide fp16, 16B rows).
template <int NP>
__global__ __launch_bounds__(256) void transform12_kernel(
    const float* __restrict__ p0, const float* __restrict__ p1,
    const float* __restrict__ p2, const float* __restrict__ p3,
    const float* __restrict__ b1, const float* __restrict__ W1,
    const float* __restrict__ W2, const float* __restrict__ dis,
    __half* __restrict__ xout, int N) {
    __shared__ float sW1[12 * 16];
    __shared__ float sW2[16 * 8];
    __shared__ float sB[16];
    if (threadIdx.x < 192) sW1[threadIdx.x] = W1[threadIdx.x];
    if (threadIdx.x < 128) sW2[threadIdx.x] = W2[threadIdx.x];
    if (threadIdx.x < 16) sB[threadIdx.x] = b1[threadIdx.x];
    __syncthreads();
    int i = blockIdx.x * blockDim.x + threadIdx.x;
    if (i >= N) return;
    float d = dis[i];
    float A[12];
#pragma unroll
    for (int q = 0; q < 3; q++) {
        float4 va = ((const float4*)(p0 + (size_t)i * 12))[q];
        float4 vb = ((const float4*)(p1 + (size_t)i * 12))[q];
        float sx = va.x + vb.x, sy = va.y + vb.y, sz = va.z + vb.z, sw = va.w + vb.w;
        if (NP == 4) {
            float4 vc = ((const float4*)(p2 + (size_t)i * 12))[q];
            float4 vd = ((const float4*)(p3 + (size_t)i * 12))[q];
            sx += vc.x + vd.x; sy += vc.y + vd.y;
            sz += vc.z + vd.z; sw += vc.w + vd.w;
        }
        A[4 * q + 0] = sx * d;
        A[4 * q + 1] = sy * d;
        A[4 * q + 2] = sz * d;
        A[4 * q + 3] = sw * d;
    }
    float h[16];
#pragma unroll
    for (int f = 0; f < 16; f++) {
        float acc = sB[f];
#pragma unroll
        for (int k = 0; k < 12; k++) acc = fmaf(A[k], sW1[k * 16 + f], acc);
        h[f] = fmaxf(acc, 0.0f);
    }
    __half2* x2 = (__half2*)xout;
#pragma unroll
    for (int k2 = 0; k2 < 4; k2++) {
        float o0 = 0.0f, o1 = 0.0f;
#pragma unroll
        for (int k = 0; k < 16; k++) {
            o0 = fmaf(h[k], sW2[k * 8 + 2 * k2], o0);
            o1 = fmaf(h[k], sW2[k * 8 + 2 * k2 + 1], o1);
        }
        x2[(size_t)i * 4 + k2] = __floats2half2_rn(o0 * d, o1 * d);
    }
}

// Layer-2 gather (8-wide, single pass): T3 = (acc*d + b2) * d -> fp16 table.
__global__ __launch_bounds__(256) void gather8_t3_kernel(
    const int2* __restrict__ rows, const int* __restrict__ col,
    const float* __restrict__ dis, const __half* __restrict__ xin,
    const float* __restrict__ b2, __half* __restrict__ xout, int N) {
    int tid = blockIdx.x * blockDim.x + threadIdx.x;
    int i = tid >> 1;
    int p = tid & 1;
    if (i >= N) return;
    int2 r = rows[i];
    float2 acc[4];
    gather_acc_rng<8, 4>(i, p, r.x, r.y, true, col, (const __half2*)xin, acc);
    float d = dis[i];
    __half2* x2o = (__half2*)xout;
#pragma unroll
    for (int k = 0; k < 4; k++) {
        if ((k >> 1) == p) {
            x2o[(size_t)i * 4 + k] =
                __floats2half2_rn((acc[k].x * d + b2[2 * k]) * d,
                                  (acc[k].y * d + b2[2 * k + 1]) * d);
        }
    }
}

// Layer-3 gather (8-wide, single pass) with fused epilogue:
//   A3 = acc*d; h = relu(A3@W3 + b3) (16); T4 = (h@W4)*d, 12 feats in
//   32B-padded rows. Lane p computes hidden slice [8p,8p+8), partial
//   12-outputs, shfl-combine; lane 0 writes feats 0..7, lane 1 feats 8..11.
__global__ __launch_bounds__(256) void gather8_t4_kernel(
    const int2* __restrict__ rows, const int* __restrict__ col,
    const float* __restrict__ dis, const __half* __restrict__ xin,
    const float* __restrict__ b3, const float* __restrict__ W3,
    const float* __restrict__ W4, __half* __restrict__ xout, int N) {
    __shared__ float sW3[8 * 16];
    __shared__ float sW4[16 * 12];
    __shared__ float sB[16];
    if (threadIdx.x < 128) sW3[threadIdx.x] = W3[threadIdx.x];
    if (threadIdx.x < 192) sW4[threadIdx.x] = W4[threadIdx.x];
    if (threadIdx.x < 16) sB[threadIdx.x] = b3[threadIdx.x];
    __syncthreads();
    int tid = blockIdx.x * blockDim.x + threadIdx.x;
    int i = tid >> 1;
    int p = tid & 1;
    if (i >= N) return;
    int2 r = rows[i];
    float2 acc[4];
    gather_acc_rng<8, 4>(i, p, r.x, r.y, true, col, (const __half2*)xin, acc);
    float d = dis[i];
    float A[8];
#pragma unroll
    for (int k = 0; k < 4; k++) {
        A[2 * k] = acc[k].x * d;
        A[2 * k + 1] = acc[k].y * d;
    }
    float h[8];
#pragma unroll
    for (int f = 0; f < 8; f++) {
        float a = sB[p * 8 + f];
#pragma unroll
        for (int k = 0; k < 8; k++) a = fmaf(A[k], sW3[k * 16 + p * 8 + f], a);
        h[f] = fmaxf(a, 0.0f);
    }
    float o[12];
#pragma unroll
    for (int j = 0; j < 12; j++) {
        float a = 0.0f;
#pragma unroll
        for (int f = 0; f < 8; f++) a = fmaf(h[f], sW4[(p * 8 + f) * 12 + j], a);
        o[j] = a;
    }
#pragma unroll
    for (int j = 0; j < 12; j++) o[j] += __shfl_xor(o[j], 1);
    __half2* x2o = (__half2*)xout;
    if (p == 0) {
#pragma unroll
        for (int k = 0; k < 4; k++) {
            x2o[(size_t)i * 8 + k] =
                __floats2half2_rn(o[2 * k] * d, o[2 * k + 1] * d);
        }
    } else {
#pragma unroll
        for (int k = 0; k < 2; k++) {
            x2o[(size_t)i * 8 + 4 + k] =
                __floats2half2_rn(o[8 + 2 * k] * d, o[9 + 2 * k] * d);
        }
    }
}

// Layer-4 tail: out = sigmoid((sum of NP partials)*d + b4), 12-wide.
template <int NP>
__global__ __launch_bounds__(256) void combine_sig_kernel(
    const float* __restrict__ p0, const float* __restrict__ p1,
    const float* __restrict__ p2, const float* __restrict__ p3,
    const float* __restrict__ dis, const float* __restrict__ bias,
    float* __restrict__ out, int N) {
    __shared__ float sB[12];
    if (threadIdx.x < 12) sB[threadIdx.x] = bias[threadIdx.x];
    __syncthreads();
    int i = blockIdx.x * blockDim.x + threadIdx.x;
    if (i >= N) return;
    float d = dis[i];
    float4* o4 = (float4*)(out + (size_t)i * 12);
#pragma unroll
    for (int q = 0; q < 3; q++) {
        float4 va = ((const float4*)(p0 + (size_t)i * 12))[q];
        float4 vb = ((const float4*)(p1 + (size_t)i * 12))[q];
        float sx = va.x + vb.x, sy = va.y + vb.y, sz = va.z + vb.z, sw = va.w + vb.w;
        if (NP == 4) {
            float4 vc = ((const float4*)(p2 + (size_t)i * 12))[q];
            float4 vd = ((const float4*)(p3 + (size_t)i * 12))[q];
            sx += vc.x + vd.x; sy += vc.y + vd.y;
            sz += vc.z + vd.z; sw += vc.w + vd.w;
        }
        float4 r;
        r.x = 1.0f / (1.0f + expf(-(sx * d + sB[4 * q + 0])));
        r.y = 1.0f / (1.0f + expf(-(sy * d + sB[4 * q + 1])));
        r.z = 1.0f / (1.0f + expf(-(sz * d + sB[4 * q + 2])));
        r.w = 1.0f / (1.0f + expf(-(sw * d + sB[4 * q + 3])));
        o4[q] = r;
    }
}

static inline size_t align_up(size_t v, size_t a) { return (v + a - 1) & ~(a - 1); }

extern "C" void kernel_launch(void* const* d_in, const int* in_sizes, int n_in,
                              void* d_out, int out_size, void* d_ws, size_t ws_size,
                              hipStream_t stream) {
    const float* x  = (const float*)d_in[0];
    const int*   ei = (const int*)d_in[1];
    const float* W1 = (const float*)d_in[2];
    const float* b1 = (const float*)d_in[3];
    const float* W2 = (const float*)d_in[4];
    const float* b2 = (const float*)d_in[5];
    const float* W3 = (const float*)d_in[6];
    const float* b3 = (const float*)d_in[7];
    const float* W4 = (const float*)d_in[8];
    const float* b4 = (const float*)d_in[9];
    float* out = (float*)d_out;

    const int N = in_sizes[0] / 12;
    const int E = in_sizes[1] / 2;
    const int qN = (N + 3) >> 2;      // quarter size (q = s / qN, 0..3)
    const int* src = ei;       // edge_index[0]
    const int* dst = ei + E;   // edge_index[1]
    const int NB = (N + NPB - 1) / NPB;  // 196

    // Workspace carve-up; part0/1 alias the dead binned[] region, part2/3
    // are fresh (used only if ws_size permits; else 2-way fallback).
    char* ws = (char*)d_ws;
    size_t off = 0;
    int* bucket_cur = (int*)(ws + off);   off = align_up(off + (size_t)NB * 4, 256);
    int2* rows = (int2*)(ws + off);       off = align_up(off + (size_t)N * 8, 256);
    int4* qmids = (int4*)(ws + off);      off = align_up(off + (size_t)N * 16, 256);
    float* dis = (float*)(ws + off);      off = align_up(off + (size_t)N * 4, 256);
    unsigned int* binned = (unsigned int*)(ws + off);
    off = align_up(off + ((size_t)NB * CAP + 4096) * 4, 256);
    int* col = (int*)(ws + off);          off = align_up(off + ((size_t)NB * CAP + 4096) * 4, 256);
    __half* xls = (__half*)(ws + off);    off = align_up(off + (size_t)N * 16 * 2, 256);
    __half* xls2 = (__half*)(ws + off);   off = align_up(off + (size_t)N * 16 * 2, 256);
    size_t off23 = off;
    float* part2 = (float*)(ws + off23);
    size_t off_end = align_up(off23 + (size_t)N * 24 * 4, 256);
    const bool use4 = (off_end <= ws_size);
    float* part3 = part2 + (size_t)N * 12;
    (void)n_in; (void)out_size;

    // part0/1 (2 x N x 12 fp32 = 19.2 MB) alias binned (20.7 MB): binned is
    // dead after csr_bucket_t1_kernel completes (stream-ordered).
    float* part0 = (float*)binned;
    float* part1 = part0 + (size_t)N * 12;

    const int B = 256;
    auto blocks = [&](long long n) { return (int)((n + B - 1) / B); };
    int R = blocks(2LL * N);            // lane-pair ranges
    R = (R + 3) & ~3;                   // multiple of 4 (fits both decodes)

    // --- CSR build (src-quarter partitioned rows) + fused T1 = x*dis -----
    init_cur_kernel<<<1, 256, 0, stream>>>(bucket_cur, NB);
    bin_kernel<<<(E + BIN_CHUNK - 1) / BIN_CHUNK, BIN_TH, 0, stream>>>(src, dst, bucket_cur, binned, E, NB);
    csr_bucket_t1_kernel<<<NB, 1024, 0, stream>>>(binned, bucket_cur, rows, qmids, dis,
                                                  col, x, xls, N, qN);

    // --- Layer 1: single-visit src-partitioned gather (12-wide) ----------
    if (use4) {
        gather12p_kernel<4><<<R * 4, B, 0, stream>>>(rows, qmids, col, xls,
                                                     part0, part1, part2, part3, N, qN);
        transform12_kernel<4><<<blocks(N), B, 0, stream>>>(part0, part1, part2, part3,
                                                           b1, W1, W2, dis, xls2, N);
    } else {
        gather12p_kernel<2><<<R * 2, B, 0, stream>>>(rows, qmids, col, xls,
                                                     part0, part1, part0, part1, N, qN);
        transform12_kernel<2><<<blocks(N), B, 0, stream>>>(part0, part1, part0, part1,
                                                           b1, W1, W2, dis, xls2, N);
    }

    // --- Layer 2: single-pass 8-wide gather -> T3 (xls) ------------------
    gather8_t3_kernel<<<blocks(2LL * N), B, 0, stream>>>(rows, col, dis, xls2, b2, xls, N);

    // --- Layer 3: single-pass 8-wide gather + fused W3/relu/W4 -> T4 (xls2)
    gather8_t4_kernel<<<blocks(2LL * N), B, 0, stream>>>(rows, col, dis, xls, b3, W3, W4,
                                                         xls2, N);

    // --- Layer 4: single-visit src-partitioned gather (12-wide) ----------
    if (use4) {
        gather12p_kernel<4><<<R * 4, B, 0, stream>>>(rows, qmids, col, xls2,
                                                     part0, part1, part2, part3, N, qN);
        combine_sig_kernel<4><<<blocks(N), B, 0, stream>>>(part0, part1, part2, part3,
                                                           dis, b4, out, N);
    } else {
        gather12p_kernel<2><<<R * 2, B, 0, stream>>>(rows, qmids, col, xls2,
                                                     part0, part1, part0, part1, N, qN);
        combine_sig_kernel<2><<<blocks(N), B, 0, stream>>>(part0, part1, part0, part1,
                                                           dis, b4, out, N);
    }
}

// Round 8
// 358.807 us; speedup vs baseline: 1.1914x; 1.0189x over previous
//
#include <hip/hip_runtime.h>
#include <hip/hip_fp16.h>
#include <math.h>

// ---------------------------------------------------------------------------
// GCN autoencoder: 4 layers (12->16->8->16->12), N=200K nodes, E=5M edges.
//
// Round 23 (on R19's 360 us; R22 4-way slicing was net-neutral -> reverted
// to R19's 2-way src-half single-visit 12-wide gathers):
// ATTACK THE BUILD PHASE (bin+csr ~ 95-110 us by subtraction, never in
// top-5):
//   * NPB 1024 -> 512: 391 csr WGs x 512 thr, colbuf 54 KB -> ~63 KB LDS
//     -> 2 WGs/CU, ALL buckets resident at once (was 196 WGs, 1/CU, 77%
//     of CUs used); per-WG serial chain halves.
//   * BIN_CHUNK 4096 -> 8192 (EPT 16): half the bin WGs, half the scan +
//     bucket_cur atomic overhead, 2x longer coalesced runs per bucket.
//   * Record = (src<<9)|local (27 bits); bucket-id staging -> ushort.
// Gather structure identical to R19.
// ---------------------------------------------------------------------------

#define NPB 512                // nodes per bucket; bucket id = dst >> 9
#define MAX_NB 512             // supports N <= 262144
#define CAP 13504              // bucket region capacity (mean 12800 + ~6s)
#define BIN_CHUNK 8192         // edges per workgroup in bin_kernel
#define BIN_TH 512             // threads per workgroup in bin_kernel
#define EPT (BIN_CHUNK / BIN_TH)  // edges per thread (16)
#define MAXB CAP               // LDS col staging capacity (full bucket)

__global__ void init_cur_kernel(int* __restrict__ bucket_cur, int NB) {
    int t = blockIdx.x * blockDim.x + threadIdx.x;
    if (t < NB) bucket_cur[t] = t * CAP;
}

// Block-level LDS counting sort of an 8192-edge chunk (512 threads).
__global__ __launch_bounds__(BIN_TH) void bin_kernel(const int* __restrict__ src,
                                                     const int* __restrict__ dst,
                                                     int* __restrict__ bucket_cur,
                                                     unsigned int* __restrict__ binned,
                                                     int E, int NB) {
    __shared__ int h[MAX_NB];          // hist, then reused as scatter cursor
    __shared__ int scl[MAX_NB + 1];    // block-local exclusive offsets
    __shared__ int base[MAX_NB];       // global run bases
    __shared__ int sscan[BIN_TH];
    __shared__ unsigned int stage[BIN_CHUNK];       // 32 KB
    __shared__ unsigned short bkt16[BIN_CHUNK];     // 16 KB bucket ids
    int cbeg = blockIdx.x * BIN_CHUNK;
    int cend = min(cbeg + BIN_CHUNK, E);
    int chunk_n = cend - cbeg;
    int tid = threadIdx.x;

    for (int t = tid; t < NB; t += BIN_TH) h[t] = 0;
    __syncthreads();
    int myd[EPT];
#pragma unroll
    for (int j = 0; j < EPT; j++) {
        int e = cbeg + tid + j * BIN_TH;
        if (e < cend) {
            myd[j] = dst[e];
            atomicAdd(&h[myd[j] >> 9], 1);
        }
    }
    __syncthreads();
    int v = (tid < NB) ? h[tid] : 0;
    sscan[tid] = v;
    __syncthreads();
    for (int off = 1; off < BIN_TH; off <<= 1) {
        int t = (tid >= off) ? sscan[tid - off] : 0;
        __syncthreads();
        sscan[tid] += t;
        __syncthreads();
    }
    if (tid < NB) {
        scl[tid] = sscan[tid] - v;
        base[tid] = v ? atomicAdd(&bucket_cur[tid], v) : 0;
    }
    if (tid == 0) scl[NB] = chunk_n;
    __syncthreads();
    for (int t = tid; t < NB; t += BIN_TH) h[t] = 0;  // reuse as cursor
    __syncthreads();
#pragma unroll
    for (int j = 0; j < EPT; j++) {
        int e = cbeg + tid + j * BIN_TH;
        if (e < cend) {
            int d = myd[j];
            int bkt = d >> 9;
            int pos = scl[bkt] + atomicAdd(&h[bkt], 1);
            stage[pos] = ((unsigned)src[e] << 9) | (unsigned)(d & 511);
            bkt16[pos] = (unsigned short)bkt;
        }
    }
    __syncthreads();
    for (int k = tid; k < chunk_n; k += BIN_TH) {
        int bkt = bkt16[k];
        binned[base[bkt] + (k - scl[bkt])] = stage[k];
    }
}

// One WG per bucket (512 nodes, 512 threads, ~63 KB LDS -> 2 WGs/CU):
// per-node count + scan, rows/mids/dis emit, 2-way src-half partitioned
// scatter into LDS colbuf, coalesced flush.
// FUSED T1 tail: T1 = x*dis, 12 feats in 32B-padded rows.
__global__ __launch_bounds__(512) void csr_bucket_t1_kernel(
    const unsigned int* __restrict__ binned,
    const int* __restrict__ bucket_cur,
    int2* __restrict__ rows, int* __restrict__ mids, float* __restrict__ dis,
    int* __restrict__ col,
    const float* __restrict__ x,
    __half* __restrict__ xls, int N, int halfN) {
    __shared__ int cnt[NPB];
    __shared__ int cnt0[NPB];
    __shared__ int curA[NPB];
    __shared__ int curB[NPB];
    __shared__ int colbuf[MAXB];   // 54 KB (total ~62.7 KB LDS)
    int b = blockIdx.x;
    int nbase = b << 9;
    int nlocal = min(NPB, N - nbase);
    int beg = b * CAP;
    int bsize = bucket_cur[b] - beg;
    int tid = threadIdx.x;

    cnt[tid] = 0;
    cnt0[tid] = 0;
    __syncthreads();
    for (int k = tid; k < bsize; k += 512) {
        unsigned rec = binned[beg + k];
        int l = rec & 511u;
        int s = (int)(rec >> 9);
        atomicAdd(&cnt[l], 1);
        if (s < halfN) atomicAdd(&cnt0[l], 1);
    }
    __syncthreads();
    int v = cnt[tid];
    int v0 = cnt0[tid];
    curA[tid] = v;
    __syncthreads();
    for (int off = 1; off < 512; off <<= 1) {
        int t = (tid >= off) ? curA[tid - off] : 0;
        __syncthreads();
        curA[tid] += t;
        __syncthreads();
    }
    int excl = curA[tid] - v;
    float d = 1.0f / sqrtf((float)(v + 1));  // +1 self-loop
    if (tid < nlocal) {
        rows[nbase + tid] = make_int2(beg + excl, beg + excl + v);
        mids[nbase + tid] = beg + excl + v0;
        dis[nbase + tid] = d;
    }
    __syncthreads();
    curA[tid] = excl;          // cursor for src < halfN
    curB[tid] = excl + v0;     // cursor for src >= halfN
    __syncthreads();
    if (bsize <= MAXB) {
        for (int k = tid; k < bsize; k += 512) {
            unsigned rec = binned[beg + k];
            int l = rec & 511u;
            int s = (int)(rec >> 9);
            int pos = (s < halfN) ? atomicAdd(&curA[l], 1)
                                  : atomicAdd(&curB[l], 1);
            colbuf[pos] = s;
        }
        __syncthreads();
        for (int k = tid; k < bsize; k += 512) col[beg + k] = colbuf[k];
    } else {  // cannot trigger with CAP sizing; correctness fallback
        for (int k = tid; k < bsize; k += 512) {
            unsigned rec = binned[beg + k];
            int l = rec & 511u;
            int s = (int)(rec >> 9);
            int pos = (s < halfN) ? atomicAdd(&curA[l], 1)
                                  : atomicAdd(&curB[l], 1);
            col[beg + pos] = s;
        }
    }
    // ---- fused T1 = x * dis, 12 feats in 32B-padded rows (stride 16) ----
    if (tid < nlocal) {
        int i = nbase + tid;
        float h[12];
#pragma unroll
        for (int k = 0; k < 12; k++) h[k] = x[(size_t)i * 12 + k];
        __half2* x2 = (__half2*)xls;
#pragma unroll
        for (int k = 0; k < 6; k++) {
            x2[(size_t)i * 8 + k] =
                __floats2half2_rn(h[2 * k] * d, h[2 * k + 1] * d);
        }
    }
}

// Accumulate one source node's P half2-features (row stride S half2s).
template <int P, int S>
__device__ __forceinline__ void acc_node(const __half2* __restrict__ x2, int c,
                                         float2 (&acc)[P]) {
    __half2 t[P];
#pragma unroll
    for (int k = 0; k < P; k++) t[k] = x2[(size_t)c * S + k];
#pragma unroll
    for (int k = 0; k < P; k++) {
        float2 v = __half22float2(t[k]);
        acc[k].x += v.x;
        acc[k].y += v.y;
    }
}

template <int P, int S>
__device__ __forceinline__ void acc_quad(const __half2* __restrict__ x2, int4 c,
                                         float2 (&acc)[P]) {
    __half2 t[4][P];
#pragma unroll
    for (int k = 0; k < P; k++) t[0][k] = x2[(size_t)c.x * S + k];
#pragma unroll
    for (int k = 0; k < P; k++) t[1][k] = x2[(size_t)c.y * S + k];
#pragma unroll
    for (int k = 0; k < P; k++) t[2][k] = x2[(size_t)c.z * S + k];
#pragma unroll
    for (int k = 0; k < P; k++) t[3][k] = x2[(size_t)c.w * S + k];
#pragma unroll
    for (int k = 0; k < P; k++) {
        float2 a0 = __half22float2(t[0][k]), a1 = __half22float2(t[1][k]);
        float2 a2 = __half22float2(t[2][k]), a3 = __half22float2(t[3][k]);
        acc[k].x += (a0.x + a1.x) + (a2.x + a3.x);
        acc[k].y += (a0.y + a1.y) + (a2.y + a3.y);
    }
}

// Core gather over an explicit [beg,end) col sub-range: lane-pair per node,
// 16B-aligned int4 col quads, UN quads in flight per lane, shfl-combined.
// UN=3 for P<=4 (proven sweet spot), UN=2 for P=6 (bound VGPRs).
// Self-loop contribution added iff `self` (by lane 0 only).
template <int C, int S>
__device__ __forceinline__ void gather_acc_rng(
    int i, int p, int beg, int end, bool self,
    const int* __restrict__ col, const __half2* __restrict__ x2,
    float2 (&acc)[C / 2]) {
    constexpr int P = C / 2;
    constexpr int UN = (P >= 6) ? 2 : 3;
#pragma unroll
    for (int k = 0; k < P; k++) {
        if (self && p == 0) acc[k] = __half22float2(x2[(size_t)i * S + k]);
        else acc[k] = make_float2(0.0f, 0.0f);
    }
    int nedge = end - beg;
    int pre = (4 - (beg & 3)) & 3;
    if (pre > nedge) pre = nedge;
    for (int j = p; j < pre; j += 2) acc_node<P, S>(x2, col[beg + j], acc);
    int abeg = beg + pre;
    int nq = (end - abeg) >> 2;  // full aligned quads
    int q = p;
    for (; q + 2 * (UN - 1) < nq; q += 2 * UN) {
        int4 cs[UN];
#pragma unroll
        for (int u = 0; u < UN; u++)
            cs[u] = *reinterpret_cast<const int4*>(col + abeg + 4 * (q + 2 * u));
#pragma unroll
        for (int u = 0; u < UN; u++) acc_quad<P, S>(x2, cs[u], acc);
    }
    for (; q < nq; q += 2) {
        int4 ca = *reinterpret_cast<const int4*>(col + abeg + 4 * q);
        acc_quad<P, S>(x2, ca, acc);
    }
    int tbeg = abeg + 4 * nq;
    for (int j = tbeg + p; j < end; j += 2) acc_node<P, S>(x2, col[j], acc);
#pragma unroll
    for (int k = 0; k < P; k++) {
        acc[k].x += __shfl_xor(acc[k].x, 1);
        acc[k].y += __shfl_xor(acc[k].y, 1);
    }
}

// 12-wide single-visit gather, src-half partitioned. chunk = (blockIdx&7)>=4
// (XCD-affine): chunk c walks sublist c of each row against table half c
// (3.2 MB slice, L2-resident). Writes raw partial sums (no dis scale).
__global__ __launch_bounds__(256) void gather12h_kernel(
    const int2* __restrict__ rows, const int* __restrict__ mids,
    const int* __restrict__ col, const __half* __restrict__ xin,
    float* __restrict__ part0, float* __restrict__ part1, int N, int halfN) {
    int grp = blockIdx.x >> 3;
    int sub = blockIdx.x & 7;
    int chunk = sub >> 2;
    int range = (grp << 2) + (sub & 3);
    int t2 = range * 256 + (int)threadIdx.x;
    int i = t2 >> 1;
    int p = t2 & 1;
    if (i >= N) return;
    int2 r = rows[i];
    int m = mids[i];
    int beg = chunk ? m : r.x;
    int end = chunk ? r.y : m;
    bool self = chunk ? (i >= halfN) : (i < halfN);
    float2 acc[6];
    gather_acc_rng<12, 8>(i, p, beg, end, self, col, (const __half2*)xin, acc);
    float* part = chunk ? part1 : part0;
    float2* ap = (float2*)(part + (size_t)i * 12);
#pragma unroll
    for (int k = 0; k < 6; k++) {
        if ((k & 1) == p) ap[k] = acc[k];
    }
}

// Layer-1 tail: A1 = (part0+part1)*d -> relu(A1@W1+b1) -> @W2 -> *dis
// -> T2 table (8-wide fp16, 16B rows).
__global__ __launch_bounds__(256) void transform12_kernel(
    const float* __restrict__ p0, const float* __restrict__ p1,
    const float* __restrict__ b1, const float* __restrict__ W1,
    const float* __restrict__ W2, const float* __restrict__ dis,
    __half* __restrict__ xout, int N) {
    __shared__ float sW1[12 * 16];
    __shared__ float sW2[16 * 8];
    __shared__ float sB[16];
    if (threadIdx.x < 192) sW1[threadIdx.x] = W1[threadIdx.x];
    if (threadIdx.x < 128) sW2[threadIdx.x] = W2[threadIdx.x];
    if (threadIdx.x < 16) sB[threadIdx.x] = b1[threadIdx.x];
    __syncthreads();
    int i = blockIdx.x * blockDim.x + threadIdx.x;
    if (i >= N) return;
    float d = dis[i];
    float A[12];
    const float4* a4 = (const float4*)(p0 + (size_t)i * 12);
    const float4* b4 = (const float4*)(p1 + (size_t)i * 12);
#pragma unroll
    for (int q = 0; q < 3; q++) {
        float4 va = a4[q], vb = b4[q];
        A[4 * q + 0] = (va.x + vb.x) * d;
        A[4 * q + 1] = (va.y + vb.y) * d;
        A[4 * q + 2] = (va.z + vb.z) * d;
        A[4 * q + 3] = (va.w + vb.w) * d;
    }
    float h[16];
#pragma unroll
    for (int f = 0; f < 16; f++) {
        float acc = sB[f];
#pragma unroll
        for (int k = 0; k < 12; k++) acc = fmaf(A[k], sW1[k * 16 + f], acc);
        h[f] = fmaxf(acc, 0.0f);
    }
    __half2* x2 = (__half2*)xout;
#pragma unroll
    for (int k2 = 0; k2 < 4; k2++) {
        float o0 = 0.0f, o1 = 0.0f;
#pragma unroll
        for (int k = 0; k < 16; k++) {
            o0 = fmaf(h[k], sW2[k * 8 + 2 * k2], o0);
            o1 = fmaf(h[k], sW2[k * 8 + 2 * k2 + 1], o1);
        }
        x2[(size_t)i * 4 + k2] = __floats2half2_rn(o0 * d, o1 * d);
    }
}

// Layer-2 gather (8-wide, single pass): T3 = (acc*d + b2) * d -> fp16 table.
__global__ __launch_bounds__(256) void gather8_t3_kernel(
    const int2* __restrict__ rows, const int* __restrict__ col,
    const float* __restrict__ dis, const __half* __restrict__ xin,
    const float* __restrict__ b2, __half* __restrict__ xout, int N) {
    int tid = blockIdx.x * blockDim.x + threadIdx.x;
    int i = tid >> 1;
    int p = tid & 1;
    if (i >= N) return;
    int2 r = rows[i];
    float2 acc[4];
    gather_acc_rng<8, 4>(i, p, r.x, r.y, true, col, (const __half2*)xin, acc);
    float d = dis[i];
    __half2* x2o = (__half2*)xout;
#pragma unroll
    for (int k = 0; k < 4; k++) {
        if ((k >> 1) == p) {
            x2o[(size_t)i * 4 + k] =
                __floats2half2_rn((acc[k].x * d + b2[2 * k]) * d,
                                  (acc[k].y * d + b2[2 * k + 1]) * d);
        }
    }
}

// Layer-3 gather (8-wide, single pass) with fused epilogue:
//   A3 = acc*d; h = relu(A3@W3 + b3) (16); T4 = (h@W4)*d, 12 feats in
//   32B-padded rows. Lane p computes hidden slice [8p,8p+8), partial
//   12-outputs, shfl-combine; lane 0 writes feats 0..7, lane 1 feats 8..11.
__global__ __launch_bounds__(256) void gather8_t4_kernel(
    const int2* __restrict__ rows, const int* __restrict__ col,
    const float* __restrict__ dis, const __half* __restrict__ xin,
    const float* __restrict__ b3, const float* __restrict__ W3,
    const float* __restrict__ W4, __half* __restrict__ xout, int N) {
    __shared__ float sW3[8 * 16];
    __shared__ float sW4[16 * 12];
    __shared__ float sB[16];
    if (threadIdx.x < 128) sW3[threadIdx.x] = W3[threadIdx.x];
    if (threadIdx.x < 192) sW4[threadIdx.x] = W4[threadIdx.x];
    if (threadIdx.x < 16) sB[threadIdx.x] = b3[threadIdx.x];
    __syncthreads();
    int tid = blockIdx.x * blockDim.x + threadIdx.x;
    int i = tid >> 1;
    int p = tid & 1;
    if (i >= N) return;
    int2 r = rows[i];
    float2 acc[4];
    gather_acc_rng<8, 4>(i, p, r.x, r.y, true, col, (const __half2*)xin, acc);
    float d = dis[i];
    float A[8];
#pragma unroll
    for (int k = 0; k < 4; k++) {
        A[2 * k] = acc[k].x * d;
        A[2 * k + 1] = acc[k].y * d;
    }
    float h[8];
#pragma unroll
    for (int f = 0; f < 8; f++) {
        float a = sB[p * 8 + f];
#pragma unroll
        for (int k = 0; k < 8; k++) a = fmaf(A[k], sW3[k * 16 + p * 8 + f], a);
        h[f] = fmaxf(a, 0.0f);
    }
    float o[12];
#pragma unroll
    for (int j = 0; j < 12; j++) {
        float a = 0.0f;
#pragma unroll
        for (int f = 0; f < 8; f++) a = fmaf(h[f], sW4[(p * 8 + f) * 12 + j], a);
        o[j] = a;
    }
#pragma unroll
    for (int j = 0; j < 12; j++) o[j] += __shfl_xor(o[j], 1);
    __half2* x2o = (__half2*)xout;
    if (p == 0) {
#pragma unroll
        for (int k = 0; k < 4; k++) {
            x2o[(size_t)i * 8 + k] =
                __floats2half2_rn(o[2 * k] * d, o[2 * k + 1] * d);
        }
    } else {
#pragma unroll
        for (int k = 0; k < 2; k++) {
            x2o[(size_t)i * 8 + 4 + k] =
                __floats2half2_rn(o[8 + 2 * k] * d, o[9 + 2 * k] * d);
        }
    }
}

// Layer-4 tail: out = sigmoid((part0+part1)*d + b4), 12-wide.
__global__ __launch_bounds__(256) void combine_sig_kernel(
    const float* __restrict__ p0, const float* __restrict__ p1,
    const float* __restrict__ dis, const float* __restrict__ bias,
    float* __restrict__ out, int N) {
    __shared__ float sB[12];
    if (threadIdx.x < 12) sB[threadIdx.x] = bias[threadIdx.x];
    __syncthreads();
    int i = blockIdx.x * blockDim.x + threadIdx.x;
    if (i >= N) return;
    float d = dis[i];
    const float4* a4 = (const float4*)(p0 + (size_t)i * 12);
    const float4* b4 = (const float4*)(p1 + (size_t)i * 12);
    float4* o4 = (float4*)(out + (size_t)i * 12);
#pragma unroll
    for (int q = 0; q < 3; q++) {
        float4 va = a4[q], vb = b4[q];
        float4 r;
        r.x = 1.0f / (1.0f + expf(-((va.x + vb.x) * d + sB[4 * q + 0])));
        r.y = 1.0f / (1.0f + expf(-((va.y + vb.y) * d + sB[4 * q + 1])));
        r.z = 1.0f / (1.0f + expf(-((va.z + vb.z) * d + sB[4 * q + 2])));
        r.w = 1.0f / (1.0f + expf(-((va.w + vb.w) * d + sB[4 * q + 3])));
        o4[q] = r;
    }
}

static inline size_t align_up(size_t v, size_t a) { return (v + a - 1) & ~(a - 1); }

extern "C" void kernel_launch(void* const* d_in, const int* in_sizes, int n_in,
                              void* d_out, int out_size, void* d_ws, size_t ws_size,
                              hipStream_t stream) {
    const float* x  = (const float*)d_in[0];
    const int*   ei = (const int*)d_in[1];
    const float* W1 = (const float*)d_in[2];
    const float* b1 = (const float*)d_in[3];
    const float* W2 = (const float*)d_in[4];
    const float* b2 = (const float*)d_in[5];
    const float* W3 = (const float*)d_in[6];
    const float* b3 = (const float*)d_in[7];
    const float* W4 = (const float*)d_in[8];
    const float* b4 = (const float*)d_in[9];
    float* out = (float*)d_out;

    const int N = in_sizes[0] / 12;
    const int E = in_sizes[1] / 2;
    const int halfN = N >> 1;
    const int* src = ei;       // edge_index[0]
    const int* dst = ei + E;   // edge_index[1]
    const int NB = (N + NPB - 1) / NPB;  // 391

    // Workspace carve-up (~58 MB); partials alias the dead binned[] region.
    char* ws = (char*)d_ws;
    size_t off = 0;
    int* bucket_cur = (int*)(ws + off);   off = align_up(off + (size_t)NB * 4, 256);
    int2* rows = (int2*)(ws + off);       off = align_up(off + (size_t)N * 8, 256);
    int* mids = (int*)(ws + off);         off = align_up(off + (size_t)N * 4, 256);
    float* dis = (float*)(ws + off);      off = align_up(off + (size_t)N * 4, 256);
    unsigned int* binned = (unsigned int*)(ws + off);
    off = align_up(off + ((size_t)NB * CAP + 4096) * 4, 256);
    int* col = (int*)(ws + off);          off = align_up(off + ((size_t)NB * CAP + 4096) * 4, 256);
    __half* xls = (__half*)(ws + off);    off = align_up(off + (size_t)N * 16 * 2, 256);
    __half* xls2 = (__half*)(ws + off);   off = align_up(off + (size_t)N * 16 * 2, 256);
    (void)ws_size; (void)n_in; (void)out_size;

    // Partials (2 x N x 12 fp32 = 19.2 MB) alias binned (21.1 MB): binned is
    // dead after csr_bucket_t1_kernel completes (stream-ordered).
    float* part0 = (float*)binned;
    float* part1 = part0 + (size_t)N * 12;

    const int B = 256;
    auto blocks = [&](long long n) { return (int)((n + B - 1) / B); };
    int nb2 = blocks(2LL * N);          // ranges for merged gather
    nb2 = (nb2 + 3) & ~3;               // multiple of 4
    const int G2 = nb2 * 2;             // merged-gather grid (mult of 8)

    // --- CSR build (src-half partitioned rows) + fused T1 = x*dis --------
    init_cur_kernel<<<2, 256, 0, stream>>>(bucket_cur, NB);
    bin_kernel<<<(E + BIN_CHUNK - 1) / BIN_CHUNK, BIN_TH, 0, stream>>>(src, dst, bucket_cur, binned, E, NB);
    csr_bucket_t1_kernel<<<NB, 512, 0, stream>>>(binned, bucket_cur, rows, mids, dis,
                                                 col, x, xls, N, halfN);

    // --- Layer 1: single-visit src-half gather (12-wide) -> partials -----
    gather12h_kernel<<<G2, B, 0, stream>>>(rows, mids, col, xls, part0, part1, N, halfN);

    // --- Layer-1 tail: relu(((p0+p1)*d)@W1+b1)@W2*dis -> T2 (xls2) -------
    transform12_kernel<<<blocks(N), B, 0, stream>>>(part0, part1, b1, W1, W2, dis, xls2, N);

    // --- Layer 2: single-pass 8-wide gather -> T3 (xls) ------------------
    gather8_t3_kernel<<<blocks(2LL * N), B, 0, stream>>>(rows, col, dis, xls2, b2, xls, N);

    // --- Layer 3: single-pass 8-wide gather + fused W3/relu/W4 -> T4 (xls2)
    gather8_t4_kernel<<<blocks(2LL * N), B, 0, stream>>>(rows, col, dis, xls, b3, W3, W4,
                                                         xls2, N);

    // --- Layer 4: single-visit src-half gather (12-wide) -> partials -----
    gather12h_kernel<<<G2, B, 0, stream>>>(rows, mids, col, xls2, part0, part1, N, halfN);

    // --- Layer-4 tail: sigmoid((p0+p1)*d + b4) -> out --------------------
    combine_sig_kernel<<<blocks(N), B, 0, stream>>>(part0, part1, dis, b4, out, N);
}